// Round 4
// baseline (477.446 us; speedup 1.0000x reference)
//
#include <hip/hip_runtime.h>

#define SCALE_F 0.08838834764831845f
#define NEG_INF -1e30f

constexpr int S    = 32;
constexpr int Hq   = 32;
constexpr int Hkv  = 8;
constexpr int G    = 4;     // Hq / Hkv
constexpr int D    = 128;
constexpr int BS   = 16;    // kv positions per cache block
constexpr int BMAX = 128;   // max cache blocks per seq
constexpr int KMAX = BMAX * BS;  // 2048

// ---------------------------------------------------------------------------
// Kernel 1: per (s, kv-head, part) partial attention. PARTS compile-time.
// Key structure: all K loads for the part issued up front (MLP=CPB, phys[] in
// registers via full unroll); V loads issued BEFORE the softmax barriers so
// their latency hides behind softmax; invalid positions masked to NEG_INF so
// p=0 and no runtime trip counts exist anywhere (no scratch arrays).
// ---------------------------------------------------------------------------
template<int PARTS>
__global__ __launch_bounds__(256, 4)
void attn_part_kernel(const float* __restrict__ q_ptr,
                      const float* __restrict__ kc,
                      const float* __restrict__ vc,
                      const int*   __restrict__ bt,
                      const int*   __restrict__ slens,
                      const float* __restrict__ slopes,
                      float* __restrict__ part_acc,
                      float* __restrict__ part_m,
                      float* __restrict__ part_l)
{
    constexpr int CHUNK = KMAX / PARTS;   // kv positions per part
    constexpr int CPB   = CHUNK / BS;     // kv blocks per part (4 for PARTS=32)

    __shared__ float sm_s[G * CHUNK];     // scores, then p
    __shared__ float sm_acc[G * D];       // half-combine buffer

    const int bid  = blockIdx.x;
    const int part = bid % PARTS;
    const int sh   = bid / PARTS;         // s*Hkv + h
    const int h    = sh % Hkv;
    const int s    = sh / Hkv;

    const int seq_len   = slens[s];
    const int num_parts = (seq_len + CHUNK - 1) / CHUNK;
    if (part >= num_parts) return;

    const int tid  = threadIdx.x;
    const int kvb0 = part * CPB;

    float slope[G];
    #pragma unroll
    for (int g = 0; g < G; ++g) slope[g] = slopes[h * G + g];
    const float ctx = (float)(seq_len - 1);

    // Block-table entries: uniform index -> scalar regs; full unroll keeps
    // them out of scratch. Always in-bounds (kvb0+i <= BMAX-1); entries past
    // seq_len point at valid (wrong) blocks whose scores get masked.
    int phys[CPB];
    #pragma unroll
    for (int i = 0; i < CPB; ++i) phys[i] = bt[s * BMAX + kvb0 + i];

    // ---------------- Pass 1: scores, groups of 4 kv-blocks ----------------
    const int oo = tid >> 4;   // position within kv block (0..15)
    const int t  = tid & 15;   // d-chunk index: d = t*8 .. t*8+7

    float4 qa[G], qb[G];
    #pragma unroll
    for (int g = 0; g < G; ++g) {
        const float* qp = q_ptr + ((size_t)(s * Hq + h * G + g) * D + t * 8);
        qa[g] = ((const float4*)qp)[0];
        qb[g] = ((const float4*)qp)[1];
    }

    #pragma unroll
    for (int i0 = 0; i0 < CPB; i0 += 4) {
        float4 ka[4], kb[4];
        #pragma unroll
        for (int u = 0; u < 4; ++u) {
            const float* kp = kc + ((((size_t)phys[i0 + u] * Hkv + h) * (D / 8) + t) * BS + oo) * 8;
            ka[u] = ((const float4*)kp)[0];
            kb[u] = ((const float4*)kp)[1];
        }
        #pragma unroll
        for (int u = 0; u < 4; ++u) {
            const int i = i0 + u;
            float sc[G];
            #pragma unroll
            for (int g = 0; g < G; ++g)
                sc[g] = qa[g].x * ka[u].x + qa[g].y * ka[u].y + qa[g].z * ka[u].z + qa[g].w * ka[u].w
                      + qb[g].x * kb[u].x + qb[g].y * kb[u].y + qb[g].z * kb[u].z + qb[g].w * kb[u].w;
            #pragma unroll
            for (int g = 0; g < G; ++g) {
                #pragma unroll
                for (int msk = 8; msk >= 1; msk >>= 1)
                    sc[g] += __shfl_xor(sc[g], msk, 16);
            }
            const int kpos   = (kvb0 + i) * BS + oo;
            const bool valid = kpos < seq_len;
            if (t == 0) {
                #pragma unroll
                for (int g = 0; g < G; ++g)
                    sm_s[g * CHUNK + i * BS + oo] =
                        valid ? (SCALE_F * sc[g] + slope[g] * ((float)kpos - ctx)) : NEG_INF;
            }
        }
    }

    // ---- Issue V loads NOW: independent of softmax, latency hides behind it.
    const int d    = tid & 127;
    const int half = tid >> 7;
    float4 v[2][4];
    #pragma unroll
    for (int j = 0; j < 2 && half + 2 * j < CPB; ++j) {
        const float* vp = vc + (((size_t)phys[half + 2 * j] * Hkv + h) * D + d) * BS;
        v[j][0] = ((const float4*)vp)[0];
        v[j][1] = ((const float4*)vp)[1];
        v[j][2] = ((const float4*)vp)[2];
        v[j][3] = ((const float4*)vp)[3];
    }

    __syncthreads();

    // ---------------- softmax: wave w handles g = w ----------------
    {
        const int g    = tid >> 6;
        const int lane = tid & 63;
        float m = NEG_INF;
        #pragma unroll
        for (int j = lane; j < CHUNK; j += 64) m = fmaxf(m, sm_s[g * CHUNK + j]);
        #pragma unroll
        for (int msk = 32; msk >= 1; msk >>= 1) m = fmaxf(m, __shfl_xor(m, msk, 64));
        float l = 0.f;
        #pragma unroll
        for (int j = lane; j < CHUNK; j += 64) {
            float p = __expf(sm_s[g * CHUNK + j] - m);
            sm_s[g * CHUNK + j] = p;
            l += p;
        }
        #pragma unroll
        for (int msk = 32; msk >= 1; msk >>= 1) l += __shfl_xor(l, msk, 64);
        if (lane == 0) {
            part_m[(sh * PARTS + part) * G + g] = m;
            part_l[(sh * PARTS + part) * G + g] = l;
        }
    }
    __syncthreads();

    // ---------------- Pass 2: p @ V (invalid positions have p == 0) --------
    float acc[G] = {0.f, 0.f, 0.f, 0.f};
    #pragma unroll
    for (int jj = 0; jj < CPB / 2; ++jj) {
        const int i = half + 2 * jj;
        const int b = jj & 1;
        #pragma unroll
        for (int g = 0; g < G; ++g) {
            const float4* pp = (const float4*)(sm_s + g * CHUNK + i * BS);
            float4 p0 = pp[0], p1 = pp[1], p2 = pp[2], p3 = pp[3];
            acc[g] += p0.x * v[b][0].x + p0.y * v[b][0].y + p0.z * v[b][0].z + p0.w * v[b][0].w;
            acc[g] += p1.x * v[b][1].x + p1.y * v[b][1].y + p1.z * v[b][1].z + p1.w * v[b][1].w;
            acc[g] += p2.x * v[b][2].x + p2.y * v[b][2].y + p2.z * v[b][2].z + p2.w * v[b][2].w;
            acc[g] += p3.x * v[b][3].x + p3.y * v[b][3].y + p3.z * v[b][3].z + p3.w * v[b][3].w;
        }
        if (i + 4 < CPB) {  // refill the buffer just consumed (fallback PARTS<32)
            const float* vp = vc + (((size_t)phys[i + 4] * Hkv + h) * D + d) * BS;
            v[b][0] = ((const float4*)vp)[0];
            v[b][1] = ((const float4*)vp)[1];
            v[b][2] = ((const float4*)vp)[2];
            v[b][3] = ((const float4*)vp)[3];
        }
    }
    if (half == 1) {
        #pragma unroll
        for (int g = 0; g < G; ++g) sm_acc[g * D + d] = acc[g];
    }
    __syncthreads();
    if (half == 0) {
        float* outp = part_acc + (size_t)(sh * PARTS + part) * G * D;
        #pragma unroll
        for (int g = 0; g < G; ++g)
            outp[g * D + d] = acc[g] + sm_acc[g * D + d];
    }
}

// ---------------------------------------------------------------------------
// Kernel 2: combine partials across parts, normalize, write output.
// ---------------------------------------------------------------------------
__global__ __launch_bounds__(512)
void attn_reduce_kernel(const float* __restrict__ part_acc,
                        const float* __restrict__ part_m,
                        const float* __restrict__ part_l,
                        const int*   __restrict__ slens,
                        float* __restrict__ out,
                        int parts, int chunk)
{
    const int sh  = blockIdx.x;      // s*Hkv + h
    const int s   = sh / Hkv;
    const int tid = threadIdx.x;
    const int g   = tid >> 7;
    const int d   = tid & 127;

    const int seq_len = slens[s];
    const int np = min(parts, (seq_len + chunk - 1) / chunk);

    float M = NEG_INF;
    for (int p = 0; p < np; ++p)
        M = fmaxf(M, part_m[(sh * parts + p) * G + g]);
    float L = 0.f, acc = 0.f;
    for (int p = 0; p < np; ++p) {
        const float w = __expf(part_m[(sh * parts + p) * G + g] - M);
        L += w * part_l[(sh * parts + p) * G + g];
        acc += w * part_acc[((size_t)(sh * parts + p) * G + g) * D + d];
    }
    out[(size_t)(sh * G + g) * D + d] = acc / (L + 1e-10f);
}

extern "C" void kernel_launch(void* const* d_in, const int* in_sizes, int n_in,
                              void* d_out, int out_size, void* d_ws, size_t ws_size,
                              hipStream_t stream)
{
    const float* q   = (const float*)d_in[0];
    const float* kc  = (const float*)d_in[1];
    const float* vc  = (const float*)d_in[2];
    const int*   bt  = (const int*)d_in[3];
    const int*   sl  = (const int*)d_in[4];
    const float* slp = (const float*)d_in[5];
    // d_in[6] (query_start_len) is arange(S+1): all rows decode, identity scatter.

    auto ws_need = [](int p) {
        return (size_t)S * Hkv * p * G * (D + 2) * sizeof(float);
    };
    int parts = 32;
    while (parts > 4 && ws_need(parts) > ws_size) parts >>= 1;
    const int chunk = KMAX / parts;

    float* part_acc = (float*)d_ws;
    float* part_m   = part_acc + (size_t)S * Hkv * parts * G * D;
    float* part_l   = part_m   + (size_t)S * Hkv * parts * G;

    const dim3 grid1(S * Hkv * parts);
    switch (parts) {
    case 32: attn_part_kernel<32><<<grid1, 256, 0, stream>>>(q, kc, vc, bt, sl, slp, part_acc, part_m, part_l); break;
    case 16: attn_part_kernel<16><<<grid1, 256, 0, stream>>>(q, kc, vc, bt, sl, slp, part_acc, part_m, part_l); break;
    default: attn_part_kernel<8> <<<grid1, 256, 0, stream>>>(q, kc, vc, bt, sl, slp, part_acc, part_m, part_l); break;
    }
    attn_reduce_kernel<<<S * Hkv, 512, 0, stream>>>(
        part_acc, part_m, part_l, sl, (float*)d_out, parts, chunk);
}